// Round 1
// baseline (660.408 us; speedup 1.0000x reference)
//
#include <hip/hip_runtime.h>

#define NHEADS 12
#define HDIM   64
#define EMB    768
#define SEQ    1024
#define BATCH  4
#define MTOT   (BATCH * SEQ)

// ---------------------------------------------------------------------------
// GEMM: C = A(MxK) * W(NxK)^T, + bias, * scale.
// A row-major [M,768], W row-major [N=768,K=768] (so C = A @ W.T).
// BM=128, BN=64, BK=32; 256 threads; 8x4 micro-tile per thread.
// MODE 0: store C[m, n] plain [M,768]   (o-projection, into d_out)
// MODE 1: store into [B, H, S, D] layout (q/k/v, n = h*64+d, m = b*1024+s)
// ---------------------------------------------------------------------------
template <int MODE>
__global__ __launch_bounds__(256) void gemm_wt(
    const float* __restrict__ A, const float* __restrict__ W,
    const float* __restrict__ bias, float* __restrict__ C, float scale)
{
    __shared__ float a_s[32][132];  // [k][m] transposed, stride 132 (mult of 4)
    __shared__ float w_s[32][68];   // [k][n] transposed

    const int t  = threadIdx.x;
    const int m0 = blockIdx.x * 128;
    const int n0 = blockIdx.y * 64;

    const int r0 = (t >> 4) * 8;  // 0..120
    const int c0 = (t & 15) * 4;  // 0..60

    float acc[8][4] = {};

    for (int k0 = 0; k0 < 768; k0 += 32) {
        __syncthreads();
        // A tile: 128 rows x 32 cols = 1024 float4, 4 per thread
#pragma unroll
        for (int i = 0; i < 4; ++i) {
            int l = t + i * 256;
            int row = l >> 3;
            int c4  = (l & 7) * 4;
            float4 v = *(const float4*)(A + (size_t)(m0 + row) * 768 + k0 + c4);
            a_s[c4 + 0][row] = v.x;
            a_s[c4 + 1][row] = v.y;
            a_s[c4 + 2][row] = v.z;
            a_s[c4 + 3][row] = v.w;
        }
        // W tile: 64 rows x 32 cols = 512 float4, 2 per thread
#pragma unroll
        for (int i = 0; i < 2; ++i) {
            int l = t + i * 256;
            int row = l >> 3;
            int c4  = (l & 7) * 4;
            float4 v = *(const float4*)(W + (size_t)(n0 + row) * 768 + k0 + c4);
            w_s[c4 + 0][row] = v.x;
            w_s[c4 + 1][row] = v.y;
            w_s[c4 + 2][row] = v.z;
            w_s[c4 + 3][row] = v.w;
        }
        __syncthreads();
#pragma unroll 4
        for (int kk = 0; kk < 32; ++kk) {
            float4 a0 = *(const float4*)&a_s[kk][r0];
            float4 a1 = *(const float4*)&a_s[kk][r0 + 4];
            float4 b0 = *(const float4*)&w_s[kk][c0];
            float am[8] = {a0.x, a0.y, a0.z, a0.w, a1.x, a1.y, a1.z, a1.w};
            float bm[4] = {b0.x, b0.y, b0.z, b0.w};
#pragma unroll
            for (int i = 0; i < 8; ++i)
#pragma unroll
                for (int j = 0; j < 4; ++j)
                    acc[i][j] = fmaf(am[i], bm[j], acc[i][j]);
        }
    }

    float4 bv4 = *(const float4*)(bias + n0 + c0);
    const float bv[4] = {bv4.x, bv4.y, bv4.z, bv4.w};

#pragma unroll
    for (int i = 0; i < 8; ++i) {
        int m = m0 + r0 + i;
        float4 val;
        val.x = (acc[i][0] + bv[0]) * scale;
        val.y = (acc[i][1] + bv[1]) * scale;
        val.z = (acc[i][2] + bv[2]) * scale;
        val.w = (acc[i][3] + bv[3]) * scale;
        if (MODE == 0) {
            *(float4*)(C + (size_t)m * 768 + n0 + c0) = val;
        } else {
            int bb = m >> 10;
            int ss = m & 1023;
            int hh = n0 >> 6;  // BN=64 aligns exactly with head boundary
            *(float4*)(C + ((size_t)(bb * NHEADS + hh) * SEQ + ss) * HDIM + c0) = val;
        }
    }
}

// ---------------------------------------------------------------------------
// Fused attention: per block, one (b,h) and 64 q-rows; stream 16 K/V tiles
// of 64 with online softmax. Bias from 4-entry per-head table selected by
// positional row/col equality, computed on the fly.
// ---------------------------------------------------------------------------
__global__ __launch_bounds__(256) void attn_fused(
    const float* __restrict__ qg, const float* __restrict__ kg,
    const float* __restrict__ vg, const int* __restrict__ pos_row,
    const int* __restrict__ pos_col, const float* __restrict__ rel_table,
    float* __restrict__ outg)
{
    __shared__ float q_s[64][68];   // Q^T: [d][q]
    __shared__ float kv_s[64][68];  // K phase: K^T [d][k]; V phase: V [k][d]
    __shared__ float s_s[64][68];   // scores [q][k], then p^T [k][q]
    __shared__ float mrow[64], lrow[64], arow[64];
    __shared__ int   prq[64], pcq[64], prk[64], pck[64];

    const int t   = threadIdx.x;
    const int bh  = blockIdx.y;
    const int b   = bh / NHEADS;
    const int h   = bh - b * NHEADS;
    const int q0g = blockIdx.x * 64;

    const float* qb = qg + (size_t)bh * SEQ * HDIM;
    const float* kb = kg + (size_t)bh * SEQ * HDIM;
    const float* vb = vg + (size_t)bh * SEQ * HDIM;

    const float t0 = rel_table[0 * NHEADS + h];
    const float t1 = rel_table[1 * NHEADS + h];
    const float t2 = rel_table[2 * NHEADS + h];
    const float t3 = rel_table[3 * NHEADS + h];

    // Q tile transposed into LDS
#pragma unroll
    for (int i = 0; i < 4; ++i) {
        int l = t + i * 256;
        int row = l >> 4;
        int c4  = (l & 15) * 4;
        float4 v = *(const float4*)(qb + (size_t)(q0g + row) * HDIM + c4);
        q_s[c4 + 0][row] = v.x;
        q_s[c4 + 1][row] = v.y;
        q_s[c4 + 2][row] = v.z;
        q_s[c4 + 3][row] = v.w;
    }
    if (t < 64) {
        prq[t]  = pos_row[b * SEQ + q0g + t];
        pcq[t]  = pos_col[b * SEQ + q0g + t];
        mrow[t] = -1e30f;
        lrow[t] = 0.0f;
    }

    const int qq0 = (t >> 4) * 4;  // q offset (score & PV & epilogue)
    const int kk0 = (t & 15) * 4;  // k offset in score phase, d offset in PV

    float o_acc[4][4] = {};

    for (int kt = 0; kt < 16; ++kt) {
        const int k0g = kt * 64;
        __syncthreads();  // previous PV done before overwriting kv_s/s_s
        // K tile transposed [d][k]
#pragma unroll
        for (int i = 0; i < 4; ++i) {
            int l = t + i * 256;
            int row = l >> 4;
            int c4  = (l & 15) * 4;
            float4 v = *(const float4*)(kb + (size_t)(k0g + row) * HDIM + c4);
            kv_s[c4 + 0][row] = v.x;
            kv_s[c4 + 1][row] = v.y;
            kv_s[c4 + 2][row] = v.z;
            kv_s[c4 + 3][row] = v.w;
        }
        if (t < 64) {
            prk[t] = pos_row[b * SEQ + k0g + t];
            pck[t] = pos_col[b * SEQ + k0g + t];
        }
        __syncthreads();

        // scores: 4q x 4k per thread, outer product over d
        float sc[4][4] = {};
#pragma unroll 4
        for (int d = 0; d < 64; ++d) {
            float4 qa = *(const float4*)&q_s[d][qq0];
            float4 ka = *(const float4*)&kv_s[d][kk0];
            float qm[4] = {qa.x, qa.y, qa.z, qa.w};
            float km[4] = {ka.x, ka.y, ka.z, ka.w};
#pragma unroll
            for (int i = 0; i < 4; ++i)
#pragma unroll
                for (int j = 0; j < 4; ++j)
                    sc[i][j] = fmaf(qm[i], km[j], sc[i][j]);
        }
        // bias + write scores [q][k]
#pragma unroll
        for (int i = 0; i < 4; ++i) {
#pragma unroll
            for (int j = 0; j < 4; ++j) {
                int rr = prq[qq0 + i] - prk[kk0 + j];
                int rc = pcq[qq0 + i] - pck[kk0 + j];
                float bsel = (rr == 0) ? ((rc == 0) ? t3 : t1)
                                       : ((rc == 0) ? t2 : t0);
                sc[i][j] += bsel;
            }
            float4 wv = {sc[i][0], sc[i][1], sc[i][2], sc[i][3]};
            *(float4*)&s_s[qq0 + i][kk0] = wv;
        }
        __syncthreads();

        // online softmax: 4 threads per row, 16 k each
        const int r  = t >> 2;
        const int jj = t & 3;
        float vals[16];
        float pm = -1e30f;
#pragma unroll
        for (int i4 = 0; i4 < 4; ++i4) {
            float4 v = *(const float4*)&s_s[r][jj * 16 + i4 * 4];
            vals[i4 * 4 + 0] = v.x;
            vals[i4 * 4 + 1] = v.y;
            vals[i4 * 4 + 2] = v.z;
            vals[i4 * 4 + 3] = v.w;
        }
#pragma unroll
        for (int i = 0; i < 16; ++i) pm = fmaxf(pm, vals[i]);
        pm = fmaxf(pm, __shfl_xor(pm, 1));
        pm = fmaxf(pm, __shfl_xor(pm, 2));
        float mold = mrow[r];
        float mnew = fmaxf(mold, pm);
        float psum = 0.0f;
#pragma unroll
        for (int i = 0; i < 16; ++i) {
            vals[i] = __expf(vals[i] - mnew);
            psum += vals[i];
        }
        psum += __shfl_xor(psum, 1);
        psum += __shfl_xor(psum, 2);
        __syncthreads();  // all reads of s_s (and kv_s K-phase) complete

        if (jj == 0) {
            float alpha = __expf(mold - mnew);
            mrow[r] = mnew;
            lrow[r] = lrow[r] * alpha + psum;
            arow[r] = alpha;
        }
        // p transposed [k][q]
#pragma unroll
        for (int i = 0; i < 16; ++i) s_s[jj * 16 + i][r] = vals[i];
        // V tile [k][d] into kv_s
#pragma unroll
        for (int i = 0; i < 4; ++i) {
            int l = t + i * 256;
            int row = l >> 4;
            int c4  = (l & 15) * 4;
            *(float4*)&kv_s[row][c4] =
                *(const float4*)(vb + (size_t)(k0g + row) * HDIM + c4);
        }
        __syncthreads();

        // PV: 4q x 4d per thread, outer product over k
        float al[4];
#pragma unroll
        for (int i = 0; i < 4; ++i) al[i] = arow[qq0 + i];
#pragma unroll
        for (int i = 0; i < 4; ++i)
#pragma unroll
            for (int j = 0; j < 4; ++j) o_acc[i][j] *= al[i];
#pragma unroll 4
        for (int kk = 0; kk < 64; ++kk) {
            float4 pv = *(const float4*)&s_s[kk][qq0];
            float4 vv = *(const float4*)&kv_s[kk][kk0];
            float pmv[4] = {pv.x, pv.y, pv.z, pv.w};
            float vmv[4] = {vv.x, vv.y, vv.z, vv.w};
#pragma unroll
            for (int i = 0; i < 4; ++i)
#pragma unroll
                for (int j = 0; j < 4; ++j)
                    o_acc[i][j] = fmaf(pmv[i], vmv[j], o_acc[i][j]);
        }
    }

    __syncthreads();
#pragma unroll
    for (int i = 0; i < 4; ++i) {
        float inv = 1.0f / lrow[qq0 + i];
        float4 ov = {o_acc[i][0] * inv, o_acc[i][1] * inv,
                     o_acc[i][2] * inv, o_acc[i][3] * inv};
        *(float4*)(outg + (size_t)(b * SEQ + q0g + qq0 + i) * EMB + h * HDIM + kk0) = ov;
    }
}

// ---------------------------------------------------------------------------
extern "C" void kernel_launch(void* const* d_in, const int* in_sizes, int n_in,
                              void* d_out, int out_size, void* d_ws, size_t ws_size,
                              hipStream_t stream)
{
    const float* hs       = (const float*)d_in[0];
    const int*   pos_row  = (const int*)d_in[1];
    const int*   pos_col  = (const int*)d_in[2];
    const float* q_w      = (const float*)d_in[3];
    const float* q_b      = (const float*)d_in[4];
    const float* k_w      = (const float*)d_in[5];
    const float* k_b      = (const float*)d_in[6];
    const float* v_w      = (const float*)d_in[7];
    const float* v_b      = (const float*)d_in[8];
    const float* o_w      = (const float*)d_in[9];
    const float* o_b      = (const float*)d_in[10];
    const float* rel_tab  = (const float*)d_in[11];

    float* ws = (float*)d_ws;
    const size_t SZ = (size_t)MTOT * EMB;  // 4096*768 floats
    float* qbuf = ws;
    float* kbuf = ws + SZ;
    float* vbuf = ws + 2 * SZ;
    float* abuf = ws + 3 * SZ;

    dim3 gblk(256), ggrid(MTOT / 128, EMB / 64);

    gemm_wt<1><<<ggrid, gblk, 0, stream>>>(hs, q_w, q_b, qbuf, 0.125f);
    gemm_wt<1><<<ggrid, gblk, 0, stream>>>(hs, k_w, k_b, kbuf, 1.0f);
    gemm_wt<1><<<ggrid, gblk, 0, stream>>>(hs, v_w, v_b, vbuf, 1.0f);

    attn_fused<<<dim3(SEQ / 64, BATCH * NHEADS), gblk, 0, stream>>>(
        qbuf, kbuf, vbuf, pos_row, pos_col, rel_tab, abuf);

    gemm_wt<0><<<ggrid, gblk, 0, stream>>>(abuf, o_w, o_b, (float*)d_out, 1.0f);
}

// Round 2
// 420.149 us; speedup vs baseline: 1.5718x; 1.5718x over previous
//
#include <hip/hip_runtime.h>

#define NHEADS 12
#define HDIM   64
#define EMB    768
#define SEQ    1024
#define BATCH  4
#define MTOT   (BATCH * SEQ)

typedef __bf16 bf16x8 __attribute__((ext_vector_type(8)));
typedef float  f32x4  __attribute__((ext_vector_type(4)));

#define GLB(p) ((const __attribute__((address_space(1))) uint32_t*)(p))
#define LDS(p) ((__attribute__((address_space(3))) uint32_t*)(p))

// ---------------------------------------------------------------------------
// split f32 -> bf16 hi + bf16 lo (both RNE). x[4*n4] floats.
// ---------------------------------------------------------------------------
__global__ __launch_bounds__(256) void split_f32(
    const float* __restrict__ x, ushort* __restrict__ hi,
    ushort* __restrict__ lo, int n4)
{
    int i = blockIdx.x * 256 + threadIdx.x;
    if (i >= n4) return;
    float4 v = ((const float4*)x)[i];
    float f[4] = {v.x, v.y, v.z, v.w};
    ushort hh[4], ll[4];
#pragma unroll
    for (int j = 0; j < 4; ++j) {
        uint u = __float_as_uint(f[j]);
        ushort h = (ushort)((u + 0x7fffu + ((u >> 16) & 1u)) >> 16);
        float hf = __uint_as_float((uint)h << 16);
        uint u2 = __float_as_uint(f[j] - hf);
        ushort l = (ushort)((u2 + 0x7fffu + ((u2 >> 16) & 1u)) >> 16);
        hh[j] = h; ll[j] = l;
    }
    ushort4 hv = {hh[0], hh[1], hh[2], hh[3]};
    ushort4 lv = {ll[0], ll[1], ll[2], ll[3]};
    ((ushort4*)hi)[i] = hv;
    ((ushort4*)lo)[i] = lv;
}

// ---------------------------------------------------------------------------
// MFMA GEMM: C = A(M x 768) * W(Ntot x 768)^T, bf16 hi/lo split, 3 MFMAs.
// 128x128 tile, BK=32, 4 waves, each wave 64x64 = 4x4 frags of 16x16x32.
// global_load_lds(16B) staging, slot-XOR swizzle pre-applied on global src.
// MODE 1: fused QKV (Ntot=2304): out -> [B,H,S,D] into o0/o1/o2 by third,
//         bias b0/b1/b2 by third, scale 0.125 on third 0 (q).
// MODE 0: plain [M,768] into o0, bias b0.
// ---------------------------------------------------------------------------
template <int MODE>
__global__ __launch_bounds__(256) void gemm_mfma(
    const ushort* __restrict__ Ah, const ushort* __restrict__ Al,
    const ushort* __restrict__ Wh, const ushort* __restrict__ Wl,
    const float* __restrict__ b0, const float* __restrict__ b1,
    const float* __restrict__ b2,
    float* __restrict__ o0, float* __restrict__ o1, float* __restrict__ o2)
{
    // 4 tiles of [128 rows][32 k] bf16 = 8KB each: Ah, Al, Wh, Wl
    __shared__ __align__(16) ushort lds_buf[16384];
    char* ldsc = (char*)lds_buf;

    const int t  = threadIdx.x;
    const int w  = t >> 6;
    const int l  = t & 63;
    const int m0 = blockIdx.x * 128;
    const int n0 = blockIdx.y * 128;
    const int wm = w >> 1;   // 0..1
    const int wn = w & 1;    // 0..1

    // ---- staging geometry (2 passes of 4KB per 8KB tile) ----
    const int soff0 = w * 1024 + l * 16;
    const int soff1 = soff0 + 4096;
    const int srow0 = soff0 >> 6, srow1 = soff1 >> 6;
    const int ss0 = (((soff0 >> 4) & 3) ^ ((srow0 >> 1) & 3));
    const int ss1 = (((soff1 >> 4) & 3) ^ ((srow1 >> 1) & 3));

    const char* gb[4] = {
        (const char*)Ah + (size_t)m0 * 1536,
        (const char*)Al + (size_t)m0 * 1536,
        (const char*)Wh + (size_t)n0 * 1536,
        (const char*)Wl + (size_t)n0 * 1536};
    const size_t go0 = (size_t)srow0 * 1536 + ss0 * 16;
    const size_t go1 = (size_t)srow1 * 1536 + ss1 * 16;
    const int ldsu0 = w * 1024;          // wave-uniform byte offset in tile
    const int ldsu1 = w * 1024 + 4096;

    // ---- fragment read offsets (constant across k-steps) ----
    int aoff[4], boff[4];
#pragma unroll
    for (int i = 0; i < 4; ++i) {
        int row = wm * 64 + i * 16 + (l & 15);
        aoff[i] = row * 64 + ((((l >> 4) ^ ((row >> 1) & 3))) << 4);
        int rn = wn * 64 + i * 16 + (l & 15);
        boff[i] = rn * 64 + ((((l >> 4) ^ ((rn >> 1) & 3))) << 4);
    }

    f32x4 acc[4][4] = {};

    for (int ks = 0; ks < 24; ++ks) {
        const size_t kb = (size_t)ks * 64;
        __syncthreads();
#pragma unroll
        for (int tt = 0; tt < 4; ++tt) {
            __builtin_amdgcn_global_load_lds(GLB(gb[tt] + go0 + kb),
                                             LDS(ldsc + tt * 8192 + ldsu0), 16, 0, 0);
            __builtin_amdgcn_global_load_lds(GLB(gb[tt] + go1 + kb),
                                             LDS(ldsc + tt * 8192 + ldsu1), 16, 0, 0);
        }
        __syncthreads();

        bf16x8 ah[4], al[4], bh[4], bl[4];
#pragma unroll
        for (int i = 0; i < 4; ++i) {
            ah[i] = *(const bf16x8*)(ldsc + aoff[i]);
            al[i] = *(const bf16x8*)(ldsc + 8192 + aoff[i]);
            bh[i] = *(const bf16x8*)(ldsc + 16384 + boff[i]);
            bl[i] = *(const bf16x8*)(ldsc + 24576 + boff[i]);
        }
#pragma unroll
        for (int i = 0; i < 4; ++i)
#pragma unroll
            for (int j = 0; j < 4; ++j) {
                acc[i][j] = __builtin_amdgcn_mfma_f32_16x16x32_bf16(ah[i], bh[j], acc[i][j], 0, 0, 0);
                acc[i][j] = __builtin_amdgcn_mfma_f32_16x16x32_bf16(ah[i], bl[j], acc[i][j], 0, 0, 0);
                acc[i][j] = __builtin_amdgcn_mfma_f32_16x16x32_bf16(al[i], bh[j], acc[i][j], 0, 0, 0);
            }
    }

    // ---- epilogue: C/D frag layout col=lane&15, row=(lane>>4)*4+reg ----
    const int mrow_base = m0 + wm * 64 + ((l >> 4) << 2);

    int which = 0;
    const float* bp = b0;
    float* op = o0;
    float scale = 1.0f;
    if (MODE == 1) {
        which = (n0 >= 1536) ? 2 : (n0 >= 768 ? 1 : 0);
        bp = (which == 0) ? b0 : (which == 1 ? b1 : b2);
        op = (which == 0) ? o0 : (which == 1 ? o1 : o2);
        scale = (which == 0) ? 0.125f : 1.0f;
    }
    const int nin_base = n0 - which * 768 + wn * 64 + (l & 15);

#pragma unroll
    for (int j = 0; j < 4; ++j) {
        const int n_in = nin_base + j * 16;
        const float bv = bp[n_in];
#pragma unroll
        for (int i = 0; i < 4; ++i) {
#pragma unroll
            for (int r = 0; r < 4; ++r) {
                const int m = mrow_base + i * 16 + r;
                const float val = (acc[i][j][r] + bv) * scale;
                if (MODE == 0) {
                    op[(size_t)m * 768 + n_in] = val;
                } else {
                    const int bb = m >> 10, s = m & 1023;
                    const int h = n_in >> 6, d = n_in & 63;
                    op[((size_t)(bb * NHEADS + h) * SEQ + s) * HDIM + d] = val;
                }
            }
        }
    }
}

// ---------------------------------------------------------------------------
// Fused attention (unchanged from round 1): f32, online softmax.
// ---------------------------------------------------------------------------
__global__ __launch_bounds__(256) void attn_fused(
    const float* __restrict__ qg, const float* __restrict__ kg,
    const float* __restrict__ vg, const int* __restrict__ pos_row,
    const int* __restrict__ pos_col, const float* __restrict__ rel_table,
    float* __restrict__ outg)
{
    __shared__ float q_s[64][68];
    __shared__ float kv_s[64][68];
    __shared__ float s_s[64][68];
    __shared__ float mrow[64], lrow[64], arow[64];
    __shared__ int   prq[64], pcq[64], prk[64], pck[64];

    const int t   = threadIdx.x;
    const int bh  = blockIdx.y;
    const int b   = bh / NHEADS;
    const int h   = bh - b * NHEADS;
    const int q0g = blockIdx.x * 64;

    const float* qb = qg + (size_t)bh * SEQ * HDIM;
    const float* kb = kg + (size_t)bh * SEQ * HDIM;
    const float* vb = vg + (size_t)bh * SEQ * HDIM;

    const float t0 = rel_table[0 * NHEADS + h];
    const float t1 = rel_table[1 * NHEADS + h];
    const float t2 = rel_table[2 * NHEADS + h];
    const float t3 = rel_table[3 * NHEADS + h];

#pragma unroll
    for (int i = 0; i < 4; ++i) {
        int li = t + i * 256;
        int row = li >> 4;
        int c4  = (li & 15) * 4;
        float4 v = *(const float4*)(qb + (size_t)(q0g + row) * HDIM + c4);
        q_s[c4 + 0][row] = v.x;
        q_s[c4 + 1][row] = v.y;
        q_s[c4 + 2][row] = v.z;
        q_s[c4 + 3][row] = v.w;
    }
    if (t < 64) {
        prq[t]  = pos_row[b * SEQ + q0g + t];
        pcq[t]  = pos_col[b * SEQ + q0g + t];
        mrow[t] = -1e30f;
        lrow[t] = 0.0f;
    }

    const int qq0 = (t >> 4) * 4;
    const int kk0 = (t & 15) * 4;

    float o_acc[4][4] = {};

    for (int kt = 0; kt < 16; ++kt) {
        const int k0g = kt * 64;
        __syncthreads();
#pragma unroll
        for (int i = 0; i < 4; ++i) {
            int li = t + i * 256;
            int row = li >> 4;
            int c4  = (li & 15) * 4;
            float4 v = *(const float4*)(kb + (size_t)(k0g + row) * HDIM + c4);
            kv_s[c4 + 0][row] = v.x;
            kv_s[c4 + 1][row] = v.y;
            kv_s[c4 + 2][row] = v.z;
            kv_s[c4 + 3][row] = v.w;
        }
        if (t < 64) {
            prk[t] = pos_row[b * SEQ + k0g + t];
            pck[t] = pos_col[b * SEQ + k0g + t];
        }
        __syncthreads();

        float sc[4][4] = {};
#pragma unroll 4
        for (int d = 0; d < 64; ++d) {
            float4 qa = *(const float4*)&q_s[d][qq0];
            float4 ka = *(const float4*)&kv_s[d][kk0];
            float qm[4] = {qa.x, qa.y, qa.z, qa.w};
            float km[4] = {ka.x, ka.y, ka.z, ka.w};
#pragma unroll
            for (int i = 0; i < 4; ++i)
#pragma unroll
                for (int j = 0; j < 4; ++j)
                    sc[i][j] = fmaf(qm[i], km[j], sc[i][j]);
        }
#pragma unroll
        for (int i = 0; i < 4; ++i) {
#pragma unroll
            for (int j = 0; j < 4; ++j) {
                int rr = prq[qq0 + i] - prk[kk0 + j];
                int rc = pcq[qq0 + i] - pck[kk0 + j];
                float bsel = (rr == 0) ? ((rc == 0) ? t3 : t1)
                                       : ((rc == 0) ? t2 : t0);
                sc[i][j] += bsel;
            }
            float4 wv = {sc[i][0], sc[i][1], sc[i][2], sc[i][3]};
            *(float4*)&s_s[qq0 + i][kk0] = wv;
        }
        __syncthreads();

        const int r  = t >> 2;
        const int jj = t & 3;
        float vals[16];
        float pm = -1e30f;
#pragma unroll
        for (int i4 = 0; i4 < 4; ++i4) {
            float4 v = *(const float4*)&s_s[r][jj * 16 + i4 * 4];
            vals[i4 * 4 + 0] = v.x;
            vals[i4 * 4 + 1] = v.y;
            vals[i4 * 4 + 2] = v.z;
            vals[i4 * 4 + 3] = v.w;
        }
#pragma unroll
        for (int i = 0; i < 16; ++i) pm = fmaxf(pm, vals[i]);
        pm = fmaxf(pm, __shfl_xor(pm, 1));
        pm = fmaxf(pm, __shfl_xor(pm, 2));
        float mold = mrow[r];
        float mnew = fmaxf(mold, pm);
        float psum = 0.0f;
#pragma unroll
        for (int i = 0; i < 16; ++i) {
            vals[i] = __expf(vals[i] - mnew);
            psum += vals[i];
        }
        psum += __shfl_xor(psum, 1);
        psum += __shfl_xor(psum, 2);
        __syncthreads();

        if (jj == 0) {
            float alpha = __expf(mold - mnew);
            mrow[r] = mnew;
            lrow[r] = lrow[r] * alpha + psum;
            arow[r] = alpha;
        }
#pragma unroll
        for (int i = 0; i < 16; ++i) s_s[jj * 16 + i][r] = vals[i];
#pragma unroll
        for (int i = 0; i < 4; ++i) {
            int li = t + i * 256;
            int row = li >> 4;
            int c4  = (li & 15) * 4;
            *(float4*)&kv_s[row][c4] =
                *(const float4*)(vb + (size_t)(k0g + row) * HDIM + c4);
        }
        __syncthreads();

        float al[4];
#pragma unroll
        for (int i = 0; i < 4; ++i) al[i] = arow[qq0 + i];
#pragma unroll
        for (int i = 0; i < 4; ++i)
#pragma unroll
            for (int j = 0; j < 4; ++j) o_acc[i][j] *= al[i];
#pragma unroll 4
        for (int kk = 0; kk < 64; ++kk) {
            float4 pv = *(const float4*)&s_s[kk][qq0];
            float4 vv = *(const float4*)&kv_s[kk][kk0];
            float pmv[4] = {pv.x, pv.y, pv.z, pv.w};
            float vmv[4] = {vv.x, vv.y, vv.z, vv.w};
#pragma unroll
            for (int i = 0; i < 4; ++i)
#pragma unroll
                for (int j = 0; j < 4; ++j)
                    o_acc[i][j] = fmaf(pmv[i], vmv[j], o_acc[i][j]);
        }
    }

    __syncthreads();
#pragma unroll
    for (int i = 0; i < 4; ++i) {
        float inv = 1.0f / lrow[qq0 + i];
        float4 ov = {o_acc[i][0] * inv, o_acc[i][1] * inv,
                     o_acc[i][2] * inv, o_acc[i][3] * inv};
        *(float4*)(outg + (size_t)(b * SEQ + q0g + qq0 + i) * EMB + h * HDIM + kk0) = ov;
    }
}

// ---------------------------------------------------------------------------
extern "C" void kernel_launch(void* const* d_in, const int* in_sizes, int n_in,
                              void* d_out, int out_size, void* d_ws, size_t ws_size,
                              hipStream_t stream)
{
    const float* hs      = (const float*)d_in[0];
    const int*   pos_row = (const int*)d_in[1];
    const int*   pos_col = (const int*)d_in[2];
    const float* q_w     = (const float*)d_in[3];
    const float* q_b     = (const float*)d_in[4];
    const float* k_w     = (const float*)d_in[5];
    const float* k_b     = (const float*)d_in[6];
    const float* v_w     = (const float*)d_in[7];
    const float* v_b     = (const float*)d_in[8];
    const float* o_w     = (const float*)d_in[9];
    const float* o_b     = (const float*)d_in[10];
    const float* rel_tab = (const float*)d_in[11];

    char* ws = (char*)d_ws;
    const size_t HS_N = (size_t)MTOT * EMB;       // 3,145,728
    const size_t W_N  = (size_t)EMB * EMB;        // 589,824
    ushort* hsh = (ushort*)ws;                ws += HS_N * 2;
    ushort* hsl = (ushort*)ws;                ws += HS_N * 2;
    ushort* wch = (ushort*)ws;                ws += 3 * W_N * 2;
    ushort* wcl = (ushort*)ws;                ws += 3 * W_N * 2;
    ushort* woh = (ushort*)ws;                ws += W_N * 2;
    ushort* wol = (ushort*)ws;                ws += W_N * 2;
    ushort* aoh = (ushort*)ws;                ws += HS_N * 2;
    ushort* aol = (ushort*)ws;                ws += HS_N * 2;
    float*  qbuf = (float*)ws;                ws += HS_N * 4;
    float*  kbuf = (float*)ws;                ws += HS_N * 4;
    float*  vbuf = (float*)ws;                ws += HS_N * 4;
    float*  abuf = (float*)ws;                ws += HS_N * 4;

    split_f32<<<(int)(HS_N / 4 / 256), 256, 0, stream>>>(hs, hsh, hsl, (int)(HS_N / 4));
    split_f32<<<(int)(W_N / 4 / 256), 256, 0, stream>>>(q_w, wch, wcl, (int)(W_N / 4));
    split_f32<<<(int)(W_N / 4 / 256), 256, 0, stream>>>(k_w, wch + W_N, wcl + W_N, (int)(W_N / 4));
    split_f32<<<(int)(W_N / 4 / 256), 256, 0, stream>>>(v_w, wch + 2 * W_N, wcl + 2 * W_N, (int)(W_N / 4));
    split_f32<<<(int)(W_N / 4 / 256), 256, 0, stream>>>(o_w, woh, wol, (int)(W_N / 4));

    gemm_mfma<1><<<dim3(MTOT / 128, 2304 / 128), 256, 0, stream>>>(
        hsh, hsl, wch, wcl, q_b, k_b, v_b, qbuf, kbuf, vbuf);

    attn_fused<<<dim3(SEQ / 64, BATCH * NHEADS), 256, 0, stream>>>(
        qbuf, kbuf, vbuf, pos_row, pos_col, rel_tab, abuf);

    split_f32<<<(int)(HS_N / 4 / 256), 256, 0, stream>>>(abuf, aoh, aol, (int)(HS_N / 4));

    gemm_mfma<0><<<dim3(MTOT / 128, EMB / 128), 256, 0, stream>>>(
        aoh, aol, woh, wol, o_b, nullptr, nullptr, (float*)d_out, nullptr, nullptr);
}

// Round 3
// 243.531 us; speedup vs baseline: 2.7118x; 1.7252x over previous
//
#include <hip/hip_runtime.h>

#define NHEADS 12
#define HDIM   64
#define EMB    768
#define SEQ    1024
#define BATCH  4
#define MTOT   (BATCH * SEQ)

typedef __bf16 bf16x8 __attribute__((ext_vector_type(8)));
typedef float  f32x4  __attribute__((ext_vector_type(4)));

#define GLB(p) ((const __attribute__((address_space(1))) uint32_t*)(p))
#define LDS(p) ((__attribute__((address_space(3))) uint32_t*)(p))

__device__ __forceinline__ uint bfr(float f) {  // f32 -> bf16 bits, RNE
    uint u = __float_as_uint(f);
    return (u + 0x7fffu + ((u >> 16) & 1u)) >> 16;
}

// ---------------------------------------------------------------------------
// split f32 -> bf16 hi + bf16 lo
// ---------------------------------------------------------------------------
__global__ __launch_bounds__(256) void split_f32(
    const float* __restrict__ x, ushort* __restrict__ hi,
    ushort* __restrict__ lo, int n4)
{
    int i = blockIdx.x * 256 + threadIdx.x;
    if (i >= n4) return;
    float4 v = ((const float4*)x)[i];
    float f[4] = {v.x, v.y, v.z, v.w};
    ushort hh[4], ll[4];
#pragma unroll
    for (int j = 0; j < 4; ++j) {
        uint h = bfr(f[j]);
        float hf = __uint_as_float(h << 16);
        ll[j] = (ushort)bfr(f[j] - hf);
        hh[j] = (ushort)h;
    }
    ushort4 hv = {hh[0], hh[1], hh[2], hh[3]};
    ushort4 lv = {ll[0], ll[1], ll[2], ll[3]};
    ((ushort4*)hi)[i] = hv;
    ((ushort4*)lo)[i] = lv;
}

// ---------------------------------------------------------------------------
// MFMA GEMM: C = A(M x 768) * W(N x 768)^T, bf16 hi/lo, 3 MFMAs per product.
// MODE 1: fused QKV (N=2304): q,k -> bf16 [B,H,S,D]; v -> bf16 [B,H,D,S] (V^T)
// MODE 0: f32 [M,768] into o0 (o-projection).
// ---------------------------------------------------------------------------
template <int MODE>
__global__ __launch_bounds__(256) void gemm_mfma(
    const ushort* __restrict__ Ah, const ushort* __restrict__ Al,
    const ushort* __restrict__ Wh, const ushort* __restrict__ Wl,
    const float* __restrict__ b0, const float* __restrict__ b1,
    const float* __restrict__ b2,
    ushort* __restrict__ q16, ushort* __restrict__ k16,
    ushort* __restrict__ vT16, float* __restrict__ o0)
{
    __shared__ __align__(16) ushort lds_buf[16384];
    char* ldsc = (char*)lds_buf;

    const int t  = threadIdx.x;
    const int w  = t >> 6;
    const int l  = t & 63;
    const int m0 = blockIdx.x * 128;
    const int n0 = blockIdx.y * 128;
    const int wm = w >> 1;
    const int wn = w & 1;

    const int soff0 = w * 1024 + l * 16;
    const int soff1 = soff0 + 4096;
    const int srow0 = soff0 >> 6, srow1 = soff1 >> 6;
    const int ss0 = (((soff0 >> 4) & 3) ^ ((srow0 >> 1) & 3));
    const int ss1 = (((soff1 >> 4) & 3) ^ ((srow1 >> 1) & 3));

    const char* gb[4] = {
        (const char*)Ah + (size_t)m0 * 1536,
        (const char*)Al + (size_t)m0 * 1536,
        (const char*)Wh + (size_t)n0 * 1536,
        (const char*)Wl + (size_t)n0 * 1536};
    const size_t go0 = (size_t)srow0 * 1536 + ss0 * 16;
    const size_t go1 = (size_t)srow1 * 1536 + ss1 * 16;
    const int ldsu0 = w * 1024;
    const int ldsu1 = w * 1024 + 4096;

    int aoff[4], boff[4];
#pragma unroll
    for (int i = 0; i < 4; ++i) {
        int row = wm * 64 + i * 16 + (l & 15);
        aoff[i] = row * 64 + ((((l >> 4) ^ ((row >> 1) & 3))) << 4);
        int rn = wn * 64 + i * 16 + (l & 15);
        boff[i] = rn * 64 + ((((l >> 4) ^ ((rn >> 1) & 3))) << 4);
    }

    f32x4 acc[4][4] = {};

    for (int ks = 0; ks < 24; ++ks) {
        const size_t kb = (size_t)ks * 64;
        __syncthreads();
#pragma unroll
        for (int tt = 0; tt < 4; ++tt) {
            __builtin_amdgcn_global_load_lds(GLB(gb[tt] + go0 + kb),
                                             LDS(ldsc + tt * 8192 + ldsu0), 16, 0, 0);
            __builtin_amdgcn_global_load_lds(GLB(gb[tt] + go1 + kb),
                                             LDS(ldsc + tt * 8192 + ldsu1), 16, 0, 0);
        }
        __syncthreads();

        bf16x8 ah[4], al[4], bh[4], bl[4];
#pragma unroll
        for (int i = 0; i < 4; ++i) {
            ah[i] = *(const bf16x8*)(ldsc + aoff[i]);
            al[i] = *(const bf16x8*)(ldsc + 8192 + aoff[i]);
            bh[i] = *(const bf16x8*)(ldsc + 16384 + boff[i]);
            bl[i] = *(const bf16x8*)(ldsc + 24576 + boff[i]);
        }
#pragma unroll
        for (int i = 0; i < 4; ++i)
#pragma unroll
            for (int j = 0; j < 4; ++j) {
                acc[i][j] = __builtin_amdgcn_mfma_f32_16x16x32_bf16(ah[i], bh[j], acc[i][j], 0, 0, 0);
                acc[i][j] = __builtin_amdgcn_mfma_f32_16x16x32_bf16(ah[i], bl[j], acc[i][j], 0, 0, 0);
                acc[i][j] = __builtin_amdgcn_mfma_f32_16x16x32_bf16(al[i], bh[j], acc[i][j], 0, 0, 0);
            }
    }

    const int mrow_base = m0 + wm * 64 + ((l >> 4) << 2);

    if (MODE == 1) {
        const int which = (n0 >= 1536) ? 2 : (n0 >= 768 ? 1 : 0);
        const float* bp = (which == 0) ? b0 : (which == 1 ? b1 : b2);
        ushort* op = (which == 0) ? q16 : (which == 1 ? k16 : vT16);
        const float scale = (which == 0) ? 0.125f : 1.0f;
        const int nin_base = n0 - which * 768 + wn * 64 + (l & 15);
#pragma unroll
        for (int j = 0; j < 4; ++j) {
            const int n_in = nin_base + j * 16;
            const float bv = bp[n_in];
            const int h = n_in >> 6, d = n_in & 63;
#pragma unroll
            for (int i = 0; i < 4; ++i)
#pragma unroll
                for (int r = 0; r < 4; ++r) {
                    const int m = mrow_base + i * 16 + r;
                    const int bb = m >> 10, s = m & 1023;
                    const ushort u = (ushort)bfr((acc[i][j][r] + bv) * scale);
                    const size_t dst = (which == 2)
                        ? ((size_t)((bb * NHEADS + h) * HDIM + d) * SEQ + s)
                        : ((size_t)((bb * NHEADS + h) * SEQ + s) * HDIM + d);
                    op[dst] = u;
                }
        }
    } else {
        const int nin_base = n0 + wn * 64 + (l & 15);
#pragma unroll
        for (int j = 0; j < 4; ++j) {
            const int n_in = nin_base + j * 16;
            const float bv = b0[n_in];
#pragma unroll
            for (int i = 0; i < 4; ++i)
#pragma unroll
                for (int r = 0; r < 4; ++r) {
                    const int m = mrow_base + i * 16 + r;
                    o0[(size_t)m * 768 + n_in] = acc[i][j][r] + bv;
                }
        }
    }
}

// ---------------------------------------------------------------------------
// Flash attention, bf16 MFMA. Per block: one (b,h), 64 q rows, 4 waves x 16 q.
// Swapped QK^T (D[k][q]) -> in-lane softmax; P via swizzled wave-private LDS;
// PV with V^T tiles. All LDS tiles XOR-swizzled (byte ^= (row&7)<<4).
// ---------------------------------------------------------------------------
#define QPOFF  0        // Q tile (8KB), overlaid by per-wave P tiles (4x2KB)
#define KOFF   8192
#define VOFF   16384
#define POSOFF 24576

__global__ __launch_bounds__(256) void attn_mfma(
    const ushort* __restrict__ q16, const ushort* __restrict__ k16,
    const ushort* __restrict__ vT16, const int* __restrict__ pos_row,
    const int* __restrict__ pos_col, const float* __restrict__ rel_table,
    ushort* __restrict__ aoh, ushort* __restrict__ aol)
{
    __shared__ __align__(16) char lds[24832];

    const int t  = threadIdx.x;
    const int w  = t >> 6;
    const int l  = t & 63;
    const int bh = blockIdx.y;
    const int b  = bh / NHEADS;
    const int h  = bh - b * NHEADS;
    const int q0g = blockIdx.x * 64;

    const char* qb  = (const char*)(q16 + (size_t)bh * SEQ * HDIM);
    const char* kb  = (const char*)(k16 + (size_t)bh * SEQ * HDIM);
    const char* vtb = (const char*)(vT16 + (size_t)bh * HDIM * SEQ);

    const float t0 = rel_table[0 * NHEADS + h];
    const float t1 = rel_table[1 * NHEADS + h];
    const float t2 = rel_table[2 * NHEADS + h];
    const float t3 = rel_table[3 * NHEADS + h];

    // staging geometry: thread covers linear LDS bytes o1, o2 of each 8KB tile
    const int o1 = t * 16, o2 = o1 + 4096;
    const int r1 = o1 >> 7, r2 = o2 >> 7;
    const int kq1 = o1 ^ ((r1 & 7) << 4);            // contiguous tiles (Q,K)
    const int kq2 = o2 ^ ((r2 & 7) << 4);
    const int vs1 = r1 * 2048 + (((((o1 >> 4) & 7) ^ (r1 & 7))) << 4);  // V^T
    const int vs2 = r2 * 2048 + (((((o2 >> 4) & 7) ^ (r2 & 7))) << 4);

    // ---- stage Q (once) ----
    __builtin_amdgcn_global_load_lds(GLB(qb + (size_t)q0g * 128 + kq1),
                                     LDS(lds + QPOFF + w * 1024), 16, 0, 0);
    __builtin_amdgcn_global_load_lds(GLB(qb + (size_t)q0g * 128 + kq2),
                                     LDS(lds + QPOFF + w * 1024 + 4096), 16, 0, 0);

    const int qrow_g = q0g + w * 16 + (l & 15);
    const int pq = (pos_row[b * SEQ + qrow_g] << 8) | pos_col[b * SEQ + qrow_g];

    __syncthreads();

    bf16x8 qf[2];
    const int qrl = w * 16 + (l & 15);
#pragma unroll
    for (int ks = 0; ks < 2; ++ks)
        qf[ks] = *(const bf16x8*)(lds + QPOFF + qrl * 128 +
                                  ((((l >> 4) + 4 * ks) ^ (qrl & 7)) << 4));

    f32x4 pv[4] = {};
    float m_run = -1e30f, l_run = 0.0f;

    const int prow = l & 15;
    const int pswz = (prow & 7) << 4;
    const int pwbase = QPOFF + w * 2048 + prow * 128;

    for (int kt = 0; kt < 16; ++kt) {
        const int k0g = kt * 64;
        __syncthreads();
        __builtin_amdgcn_global_load_lds(GLB(kb + (size_t)k0g * 128 + kq1),
                                         LDS(lds + KOFF + w * 1024), 16, 0, 0);
        __builtin_amdgcn_global_load_lds(GLB(kb + (size_t)k0g * 128 + kq2),
                                         LDS(lds + KOFF + w * 1024 + 4096), 16, 0, 0);
        __builtin_amdgcn_global_load_lds(GLB(vtb + (size_t)k0g * 2 + vs1),
                                         LDS(lds + VOFF + w * 1024), 16, 0, 0);
        __builtin_amdgcn_global_load_lds(GLB(vtb + (size_t)k0g * 2 + vs2),
                                         LDS(lds + VOFF + w * 1024 + 4096), 16, 0, 0);
        if (t < 64) {
            int pr = pos_row[b * SEQ + k0g + t];
            int pc = pos_col[b * SEQ + k0g + t];
            *(int*)(lds + POSOFF + t * 4) = (pr << 8) | pc;
        }
        __syncthreads();

        // ---- QK^T (swapped): D[k][q] ----
        f32x4 sacc[4] = {};
#pragma unroll
        for (int ks = 0; ks < 2; ++ks) {
            const bf16x8 qq = qf[ks];
#pragma unroll
            for (int j = 0; j < 4; ++j) {
                const int krow = j * 16 + (l & 15);
                const bf16x8 kf = *(const bf16x8*)(lds + KOFF + krow * 128 +
                                                   ((((l >> 4) + 4 * ks) ^ (krow & 7)) << 4));
                sacc[j] = __builtin_amdgcn_mfma_f32_16x16x32_bf16(kf, qq, sacc[j], 0, 0, 0);
            }
        }

        // ---- bias + online softmax (lane q = l&15; 16 k vals in-lane) ----
        int4 pk4[4];
#pragma unroll
        for (int j = 0; j < 4; ++j)
            pk4[j] = *(const int4*)(lds + POSOFF + (l >> 4) * 16 + j * 64);

        float sv[16];
#pragma unroll
        for (int j = 0; j < 4; ++j) {
            const int pkk[4] = {pk4[j].x, pk4[j].y, pk4[j].z, pk4[j].w};
#pragma unroll
            for (int r = 0; r < 4; ++r) {
                const int dd = pq ^ pkk[r];
                const float bs = ((dd & 0xFF00) == 0)
                                     ? (((dd & 0xFF) == 0) ? t3 : t1)
                                     : (((dd & 0xFF) == 0) ? t2 : t0);
                sv[j * 4 + r] = sacc[j][r] + bs;
            }
        }
        float pm = sv[0];
#pragma unroll
        for (int i = 1; i < 16; ++i) pm = fmaxf(pm, sv[i]);
        pm = fmaxf(pm, __shfl_xor(pm, 16));
        pm = fmaxf(pm, __shfl_xor(pm, 32));
        const float mnew = fmaxf(m_run, pm);
        float psum = 0.0f;
#pragma unroll
        for (int i = 0; i < 16; ++i) {
            sv[i] = __expf(sv[i] - mnew);
            psum += sv[i];
        }
        psum += __shfl_xor(psum, 16);
        psum += __shfl_xor(psum, 32);
        const float alpha = __expf(m_run - mnew);
        l_run = l_run * alpha + psum;
        m_run = mnew;

#pragma unroll
        for (int r = 0; r < 4; ++r) {
            const float ar = __shfl(alpha, (l >> 4) * 4 + r);
#pragma unroll
            for (int i = 0; i < 4; ++i) pv[i][r] *= ar;
        }

        // ---- P -> bf16 -> wave-private swizzled LDS tile [16q][64k] ----
#pragma unroll
        for (int j = 0; j < 4; ++j)
#pragma unroll
            for (int p2 = 0; p2 < 2; ++p2) {
                const uint u = bfr(sv[j * 4 + 2 * p2]) | (bfr(sv[j * 4 + 2 * p2 + 1]) << 16);
                const int adr = pwbase + (((l >> 4) * 8 + 4 * p2 + 32 * j) ^ pswz);
                *(uint*)(lds + adr) = u;
            }

        // ---- PV: D[q][d] += P[q][k] * V^T[d][k] ----
#pragma unroll
        for (int ks = 0; ks < 2; ++ks) {
            const bf16x8 pf = *(const bf16x8*)(lds + pwbase +
                                               ((((l >> 4) + 4 * ks) << 4) ^ pswz));
#pragma unroll
            for (int i = 0; i < 4; ++i) {
                const int vrow = i * 16 + (l & 15);
                const bf16x8 vf = *(const bf16x8*)(lds + VOFF + vrow * 128 +
                                                   ((((l >> 4) + 4 * ks) ^ (vrow & 7)) << 4));
                pv[i] = __builtin_amdgcn_mfma_f32_16x16x32_bf16(pf, vf, pv[i], 0, 0, 0);
            }
        }
    }

    // ---- epilogue: out = pv / l, hi/lo bf16 split ----
    const float rinv = 1.0f / l_run;
#pragma unroll
    for (int r = 0; r < 4; ++r) {
        const float inv = __shfl(rinv, (l >> 4) * 4 + r);
        const int mrow = b * SEQ + q0g + w * 16 + (l >> 4) * 4 + r;
        const size_t base = (size_t)mrow * 768 + h * 64 + prow;
#pragma unroll
        for (int i = 0; i < 4; ++i) {
            const float o = pv[i][r] * inv;
            const uint hu = bfr(o);
            const float hf = __uint_as_float(hu << 16);
            const uint lu = bfr(o - hf);
            aoh[base + 16 * i] = (ushort)hu;
            aol[base + 16 * i] = (ushort)lu;
        }
    }
}

// ---------------------------------------------------------------------------
extern "C" void kernel_launch(void* const* d_in, const int* in_sizes, int n_in,
                              void* d_out, int out_size, void* d_ws, size_t ws_size,
                              hipStream_t stream)
{
    const float* hs      = (const float*)d_in[0];
    const int*   pos_row = (const int*)d_in[1];
    const int*   pos_col = (const int*)d_in[2];
    const float* q_w     = (const float*)d_in[3];
    const float* q_b     = (const float*)d_in[4];
    const float* k_w     = (const float*)d_in[5];
    const float* k_b     = (const float*)d_in[6];
    const float* v_w     = (const float*)d_in[7];
    const float* v_b     = (const float*)d_in[8];
    const float* o_w     = (const float*)d_in[9];
    const float* o_b     = (const float*)d_in[10];
    const float* rel_tab = (const float*)d_in[11];

    char* ws = (char*)d_ws;
    const size_t HS_N = (size_t)MTOT * EMB;   // 3,145,728
    const size_t W_N  = (size_t)EMB * EMB;    // 589,824
    ushort* hsh = (ushort*)ws;  ws += HS_N * 2;
    ushort* hsl = (ushort*)ws;  ws += HS_N * 2;
    ushort* wch = (ushort*)ws;  ws += 3 * W_N * 2;
    ushort* wcl = (ushort*)ws;  ws += 3 * W_N * 2;
    ushort* woh = (ushort*)ws;  ws += W_N * 2;
    ushort* wol = (ushort*)ws;  ws += W_N * 2;
    ushort* aoh = (ushort*)ws;  ws += HS_N * 2;
    ushort* aol = (ushort*)ws;  ws += HS_N * 2;
    ushort* q16 = (ushort*)ws;  ws += HS_N * 2;
    ushort* k16 = (ushort*)ws;  ws += HS_N * 2;
    ushort* vT16 = (ushort*)ws; ws += HS_N * 2;

    split_f32<<<(int)(HS_N / 4 / 256), 256, 0, stream>>>(hs, hsh, hsl, (int)(HS_N / 4));
    split_f32<<<(int)(W_N / 4 / 256), 256, 0, stream>>>(q_w, wch, wcl, (int)(W_N / 4));
    split_f32<<<(int)(W_N / 4 / 256), 256, 0, stream>>>(k_w, wch + W_N, wcl + W_N, (int)(W_N / 4));
    split_f32<<<(int)(W_N / 4 / 256), 256, 0, stream>>>(v_w, wch + 2 * W_N, wcl + 2 * W_N, (int)(W_N / 4));
    split_f32<<<(int)(W_N / 4 / 256), 256, 0, stream>>>(o_w, woh, wol, (int)(W_N / 4));

    gemm_mfma<1><<<dim3(MTOT / 128, 2304 / 128), 256, 0, stream>>>(
        hsh, hsl, wch, wcl, q_b, k_b, v_b, q16, k16, vT16, nullptr);

    attn_mfma<<<dim3(SEQ / 64, BATCH * NHEADS), 256, 0, stream>>>(
        q16, k16, vT16, pos_row, pos_col, rel_tab, aoh, aol);

    gemm_mfma<0><<<dim3(MTOT / 128, EMB / 128), 256, 0, stream>>>(
        aoh, aol, woh, wol, o_b, nullptr, nullptr,
        nullptr, nullptr, nullptr, (float*)d_out);
}

// Round 4
// 229.666 us; speedup vs baseline: 2.8755x; 1.0604x over previous
//
#include <hip/hip_runtime.h>

#define NHEADS 12
#define HDIM   64
#define EMB    768
#define SEQ    1024
#define BATCH  4
#define MTOT   (BATCH * SEQ)

typedef __bf16 bf16x8 __attribute__((ext_vector_type(8)));
typedef float  f32x4  __attribute__((ext_vector_type(4)));

#define GLB(p) ((const __attribute__((address_space(1))) uint32_t*)(p))
#define LDS(p) ((__attribute__((address_space(3))) uint32_t*)(p))

__device__ __forceinline__ uint bfr(float f) {  // f32 -> bf16 bits, RNE
    uint u = __float_as_uint(f);
    return (u + 0x7fffu + ((u >> 16) & 1u)) >> 16;
}

// ---------------------------------------------------------------------------
// split f32 -> bf16 hi + bf16 lo
// ---------------------------------------------------------------------------
__global__ __launch_bounds__(256) void split_f32(
    const float* __restrict__ x, ushort* __restrict__ hi,
    ushort* __restrict__ lo, int n4)
{
    int i = blockIdx.x * 256 + threadIdx.x;
    if (i >= n4) return;
    float4 v = ((const float4*)x)[i];
    float f[4] = {v.x, v.y, v.z, v.w};
    ushort hh[4], ll[4];
#pragma unroll
    for (int j = 0; j < 4; ++j) {
        uint h = bfr(f[j]);
        float hf = __uint_as_float(h << 16);
        ll[j] = (ushort)bfr(f[j] - hf);
        hh[j] = (ushort)h;
    }
    ushort4 hv = {hh[0], hh[1], hh[2], hh[3]};
    ushort4 lv = {ll[0], ll[1], ll[2], ll[3]};
    ((ushort4*)hi)[i] = hv;
    ((ushort4*)lo)[i] = lv;
}

// merged 4-weight split: blockIdx.y selects {q_w,k_w,v_w,o_w}
__global__ __launch_bounds__(256) void split_w4(
    const float* __restrict__ w0, const float* __restrict__ w1,
    const float* __restrict__ w2, const float* __restrict__ w3,
    ushort* __restrict__ wch, ushort* __restrict__ wcl,
    ushort* __restrict__ woh, ushort* __restrict__ wol, int n4)
{
    const int y = blockIdx.y;
    const float* src = (y == 0) ? w0 : (y == 1) ? w1 : (y == 2) ? w2 : w3;
    ushort* hi = (y < 3) ? (wch + (size_t)y * (EMB * EMB)) : woh;
    ushort* lo = (y < 3) ? (wcl + (size_t)y * (EMB * EMB)) : wol;
    int i = blockIdx.x * 256 + threadIdx.x;
    if (i >= n4) return;
    float4 v = ((const float4*)src)[i];
    float f[4] = {v.x, v.y, v.z, v.w};
    ushort hh[4], ll[4];
#pragma unroll
    for (int j = 0; j < 4; ++j) {
        uint h = bfr(f[j]);
        float hf = __uint_as_float(h << 16);
        ll[j] = (ushort)bfr(f[j] - hf);
        hh[j] = (ushort)h;
    }
    ushort4 hv = {hh[0], hh[1], hh[2], hh[3]};
    ushort4 lv = {ll[0], ll[1], ll[2], ll[3]};
    ((ushort4*)hi)[i] = hv;
    ((ushort4*)lo)[i] = lv;
}

// ---------------------------------------------------------------------------
// MFMA GEMM, double-buffered (1 barrier / K-step): C = A(Mx768)*W(Nx768)^T.
// BM x 128 tile, BK=32, 4 waves (2x2), bf16 hi/lo 3-MFMA products.
// MODE 1 (BM=128): QKV fused; q,k -> [B,H,S,D] bf16; v -> [B,H,D,S] bf16.
// MODE 0 (BM=64):  f32 [M,768] (o-projection).
// ---------------------------------------------------------------------------
template <int MODE, int BM>
__global__ __launch_bounds__(256) void gemm_mfma(
    const ushort* __restrict__ Ah, const ushort* __restrict__ Al,
    const ushort* __restrict__ Wh, const ushort* __restrict__ Wl,
    const float* __restrict__ b0, const float* __restrict__ b1,
    const float* __restrict__ b2,
    ushort* __restrict__ q16, ushort* __restrict__ k16,
    ushort* __restrict__ vT16, float* __restrict__ o0)
{
    constexpr int SA = BM * 64;        // bytes per A sub-tile (hi or lo)
    constexpr int SB = 8192;           // bytes per W sub-tile
    constexpr int TS = 2 * SA + 2 * SB;  // one buffer
    constexpr int MFRAG = BM / 32;
    constexpr int WMS = BM / 2;

    __shared__ __align__(16) char ldsc[2 * TS];

    const int t  = threadIdx.x;
    const int w  = t >> 6;
    const int l  = t & 63;
    const int m0 = blockIdx.x * BM;
    const int n0 = blockIdx.y * 128;
    const int wm = w >> 1;
    const int wn = w & 1;

    const char* gb[4] = {
        (const char*)Ah + (size_t)m0 * 1536,
        (const char*)Al + (size_t)m0 * 1536,
        (const char*)Wh + (size_t)n0 * 1536,
        (const char*)Wl + (size_t)n0 * 1536};

    // fragment read offsets (within one buffer)
    int aoff[MFRAG], boff[4];
#pragma unroll
    for (int i = 0; i < MFRAG; ++i) {
        int row = wm * WMS + i * 16 + (l & 15);
        aoff[i] = row * 64 + ((((l >> 4) ^ ((row >> 1) & 3))) << 4);
    }
#pragma unroll
    for (int i = 0; i < 4; ++i) {
        int rn = wn * 64 + i * 16 + (l & 15);
        boff[i] = rn * 64 + ((((l >> 4) ^ ((rn >> 1) & 3))) << 4);
    }

    // stage one K-step into buffer buf
    auto stage = [&](int ks, int buf) {
        const size_t kb = (size_t)ks * 64;
        char* dst = ldsc + buf * TS;
#pragma unroll
        for (int tt = 0; tt < 4; ++tt) {
            const int tsz  = (tt < 2) ? SA : SB;
            const int tbas = (tt == 0) ? 0 : (tt == 1) ? SA : (tt == 2) ? 2 * SA : 2 * SA + SB;
#pragma unroll
            for (int p = 0; p < tsz; p += 4096) {
                const int soff = p + w * 1024 + l * 16;
                const int srow = soff >> 6;
                const int slot = (soff >> 4) & 3;
                const size_t go = (size_t)srow * 1536 +
                                  ((slot ^ ((srow >> 1) & 3)) << 4) + kb;
                __builtin_amdgcn_global_load_lds(GLB(gb[tt] + go),
                                                 LDS(dst + tbas + p + w * 1024), 16, 0, 0);
            }
        }
    };

    f32x4 acc[MFRAG][4] = {};

    stage(0, 0);
    __syncthreads();

    for (int ks = 0; ks < 24; ++ks) {
        if (ks + 1 < 24) stage(ks + 1, (ks + 1) & 1);

        const char* cur = ldsc + (ks & 1) * TS;
        bf16x8 ah[MFRAG], al[MFRAG], bh[4], bl[4];
#pragma unroll
        for (int i = 0; i < MFRAG; ++i) {
            ah[i] = *(const bf16x8*)(cur + aoff[i]);
            al[i] = *(const bf16x8*)(cur + SA + aoff[i]);
        }
#pragma unroll
        for (int i = 0; i < 4; ++i) {
            bh[i] = *(const bf16x8*)(cur + 2 * SA + boff[i]);
            bl[i] = *(const bf16x8*)(cur + 2 * SA + SB + boff[i]);
        }
#pragma unroll
        for (int i = 0; i < MFRAG; ++i)
#pragma unroll
            for (int j = 0; j < 4; ++j) {
                acc[i][j] = __builtin_amdgcn_mfma_f32_16x16x32_bf16(ah[i], bh[j], acc[i][j], 0, 0, 0);
                acc[i][j] = __builtin_amdgcn_mfma_f32_16x16x32_bf16(ah[i], bl[j], acc[i][j], 0, 0, 0);
                acc[i][j] = __builtin_amdgcn_mfma_f32_16x16x32_bf16(al[i], bh[j], acc[i][j], 0, 0, 0);
            }
        __syncthreads();
    }

    const int mrow_base = m0 + wm * WMS + ((l >> 4) << 2);

    if (MODE == 1) {
        const int which = (n0 >= 1536) ? 2 : (n0 >= 768 ? 1 : 0);
        const float* bp = (which == 0) ? b0 : (which == 1 ? b1 : b2);
        ushort* op = (which == 0) ? q16 : (which == 1 ? k16 : vT16);
        const float scale = (which == 0) ? 0.125f : 1.0f;
        const int nin_base = n0 - which * 768 + wn * 64 + (l & 15);
#pragma unroll
        for (int j = 0; j < 4; ++j) {
            const int n_in = nin_base + j * 16;
            const float bv = bp[n_in];
            const int h = n_in >> 6, d = n_in & 63;
#pragma unroll
            for (int i = 0; i < MFRAG; ++i)
#pragma unroll
                for (int r = 0; r < 4; ++r) {
                    const int m = mrow_base + i * 16 + r;
                    const int bb = m >> 10, s = m & 1023;
                    const ushort u = (ushort)bfr((acc[i][j][r] + bv) * scale);
                    const size_t dst = (which == 2)
                        ? ((size_t)((bb * NHEADS + h) * HDIM + d) * SEQ + s)
                        : ((size_t)((bb * NHEADS + h) * SEQ + s) * HDIM + d);
                    op[dst] = u;
                }
        }
    } else {
        const int nin_base = n0 + wn * 64 + (l & 15);
#pragma unroll
        for (int j = 0; j < 4; ++j) {
            const int n_in = nin_base + j * 16;
            const float bv = b0[n_in];
#pragma unroll
            for (int i = 0; i < MFRAG; ++i)
#pragma unroll
                for (int r = 0; r < 4; ++r) {
                    const int m = mrow_base + i * 16 + r;
                    o0[(size_t)m * 768 + n_in] = acc[i][j][r] + bv;
                }
        }
    }
}

// ---------------------------------------------------------------------------
// Flash attention, bf16 MFMA, double-buffered K/V (1 barrier per tile).
// Per block: one (b,h), 64 q rows, 4 waves x 16 q. Swapped QK^T (D[k][q]),
// in-lane softmax, P via wave-private swizzled LDS, PV with V^T tiles.
// LDS: Q/P 8KB | K dbuf 2x8KB | V dbuf 2x8KB | pos dbuf 2x256B = 41.5KB
// ---------------------------------------------------------------------------
#define QPOFF  0
#define KOFF   8192
#define VOFF   24576
#define POSOFF 40960

__global__ __launch_bounds__(256) void attn_mfma(
    const ushort* __restrict__ q16, const ushort* __restrict__ k16,
    const ushort* __restrict__ vT16, const int* __restrict__ pos_row,
    const int* __restrict__ pos_col, const float* __restrict__ rel_table,
    ushort* __restrict__ aoh, ushort* __restrict__ aol)
{
    __shared__ __align__(16) char lds[41472];

    const int t  = threadIdx.x;
    const int w  = t >> 6;
    const int l  = t & 63;
    const int bh = blockIdx.y;
    const int b  = bh / NHEADS;
    const int h  = bh - b * NHEADS;
    const int q0g = blockIdx.x * 64;

    const char* qb  = (const char*)(q16 + (size_t)bh * SEQ * HDIM);
    const char* kb  = (const char*)(k16 + (size_t)bh * SEQ * HDIM);
    const char* vtb = (const char*)(vT16 + (size_t)bh * HDIM * SEQ);

    const float t0 = rel_table[0 * NHEADS + h];
    const float t1 = rel_table[1 * NHEADS + h];
    const float t2 = rel_table[2 * NHEADS + h];
    const float t3 = rel_table[3 * NHEADS + h];

    const int o1 = t * 16, o2 = o1 + 4096;
    const int r1 = o1 >> 7, r2 = o2 >> 7;
    const int kq1 = o1 ^ ((r1 & 7) << 4);
    const int kq2 = o2 ^ ((r2 & 7) << 4);
    const int vs1 = r1 * 2048 + (((((o1 >> 4) & 7) ^ (r1 & 7))) << 4);
    const int vs2 = r2 * 2048 + (((((o2 >> 4) & 7) ^ (r2 & 7))) << 4);

    auto stage_kv = [&](int kt, int buf) {
        const int k0g = kt * 64;
        __builtin_amdgcn_global_load_lds(GLB(kb + (size_t)k0g * 128 + kq1),
                                         LDS(lds + KOFF + buf * 8192 + w * 1024), 16, 0, 0);
        __builtin_amdgcn_global_load_lds(GLB(kb + (size_t)k0g * 128 + kq2),
                                         LDS(lds + KOFF + buf * 8192 + w * 1024 + 4096), 16, 0, 0);
        __builtin_amdgcn_global_load_lds(GLB(vtb + (size_t)k0g * 2 + vs1),
                                         LDS(lds + VOFF + buf * 8192 + w * 1024), 16, 0, 0);
        __builtin_amdgcn_global_load_lds(GLB(vtb + (size_t)k0g * 2 + vs2),
                                         LDS(lds + VOFF + buf * 8192 + w * 1024 + 4096), 16, 0, 0);
        if (t < 64) {
            int pr = pos_row[b * SEQ + k0g + t];
            int pc = pos_col[b * SEQ + k0g + t];
            *(int*)(lds + POSOFF + buf * 256 + t * 4) = (pr << 8) | pc;
        }
    };

    // stage Q + first K/V tile
    __builtin_amdgcn_global_load_lds(GLB(qb + (size_t)q0g * 128 + kq1),
                                     LDS(lds + QPOFF + w * 1024), 16, 0, 0);
    __builtin_amdgcn_global_load_lds(GLB(qb + (size_t)q0g * 128 + kq2),
                                     LDS(lds + QPOFF + w * 1024 + 4096), 16, 0, 0);
    stage_kv(0, 0);

    const int qrow_g = q0g + w * 16 + (l & 15);
    const int pq = (pos_row[b * SEQ + qrow_g] << 8) | pos_col[b * SEQ + qrow_g];

    __syncthreads();

    bf16x8 qf[2];
    const int qrl = w * 16 + (l & 15);
#pragma unroll
    for (int ks = 0; ks < 2; ++ks)
        qf[ks] = *(const bf16x8*)(lds + QPOFF + qrl * 128 +
                                  ((((l >> 4) + 4 * ks) ^ (qrl & 7)) << 4));

    f32x4 pv[4] = {};
    float m_run = -1e30f, l_run = 0.0f;

    const int prow = l & 15;
    const int pswz = (prow & 7) << 4;
    const int pwbase = QPOFF + w * 2048 + prow * 128;

    for (int kt = 0; kt < 16; ++kt) {
        const int cb = kt & 1;
        if (kt + 1 < 16) stage_kv(kt + 1, cb ^ 1);
        const char* kbuf = lds + KOFF + cb * 8192;
        const char* vbuf = lds + VOFF + cb * 8192;
        const char* pbuf = lds + POSOFF + cb * 256;

        // ---- QK^T (swapped): D[k][q] ----
        f32x4 sacc[4] = {};
#pragma unroll
        for (int ks = 0; ks < 2; ++ks) {
            const bf16x8 qq = qf[ks];
#pragma unroll
            for (int j = 0; j < 4; ++j) {
                const int krow = j * 16 + (l & 15);
                const bf16x8 kf = *(const bf16x8*)(kbuf + krow * 128 +
                                                   ((((l >> 4) + 4 * ks) ^ (krow & 7)) << 4));
                sacc[j] = __builtin_amdgcn_mfma_f32_16x16x32_bf16(kf, qq, sacc[j], 0, 0, 0);
            }
        }

        // ---- bias + online softmax ----
        int4 pk4[4];
#pragma unroll
        for (int j = 0; j < 4; ++j)
            pk4[j] = *(const int4*)(pbuf + (l >> 4) * 16 + j * 64);

        float sv[16];
#pragma unroll
        for (int j = 0; j < 4; ++j) {
            const int pkk[4] = {pk4[j].x, pk4[j].y, pk4[j].z, pk4[j].w};
#pragma unroll
            for (int r = 0; r < 4; ++r) {
                const int dd = pq ^ pkk[r];
                const float bs = ((dd & 0xFF00) == 0)
                                     ? (((dd & 0xFF) == 0) ? t3 : t1)
                                     : (((dd & 0xFF) == 0) ? t2 : t0);
                sv[j * 4 + r] = sacc[j][r] + bs;
            }
        }
        float pm = sv[0];
#pragma unroll
        for (int i = 1; i < 16; ++i) pm = fmaxf(pm, sv[i]);
        pm = fmaxf(pm, __shfl_xor(pm, 16));
        pm = fmaxf(pm, __shfl_xor(pm, 32));
        const float mnew = fmaxf(m_run, pm);
        float psum = 0.0f;
#pragma unroll
        for (int i = 0; i < 16; ++i) {
            sv[i] = __expf(sv[i] - mnew);
            psum += sv[i];
        }
        psum += __shfl_xor(psum, 16);
        psum += __shfl_xor(psum, 32);
        const float alpha = __expf(m_run - mnew);
        l_run = l_run * alpha + psum;
        m_run = mnew;

#pragma unroll
        for (int r = 0; r < 4; ++r) {
            const float ar = __shfl(alpha, (l >> 4) * 4 + r);
#pragma unroll
            for (int i = 0; i < 4; ++i) pv[i][r] *= ar;
        }

        // ---- P -> bf16 -> wave-private swizzled LDS ----
#pragma unroll
        for (int j = 0; j < 4; ++j)
#pragma unroll
            for (int p2 = 0; p2 < 2; ++p2) {
                const uint u = bfr(sv[j * 4 + 2 * p2]) | (bfr(sv[j * 4 + 2 * p2 + 1]) << 16);
                const int adr = pwbase + (((l >> 4) * 8 + 4 * p2 + 32 * j) ^ pswz);
                *(uint*)(lds + adr) = u;
            }

        // ---- PV: D[q][d] += P[q][k] * V^T[d][k] ----
#pragma unroll
        for (int ks = 0; ks < 2; ++ks) {
            const bf16x8 pf = *(const bf16x8*)(lds + pwbase +
                                               ((((l >> 4) + 4 * ks) << 4) ^ pswz));
#pragma unroll
            for (int i = 0; i < 4; ++i) {
                const int vrow = i * 16 + (l & 15);
                const bf16x8 vf = *(const bf16x8*)(vbuf + vrow * 128 +
                                                   ((((l >> 4) + 4 * ks) ^ (vrow & 7)) << 4));
                pv[i] = __builtin_amdgcn_mfma_f32_16x16x32_bf16(pf, vf, pv[i], 0, 0, 0);
            }
        }
        __syncthreads();
    }

    // ---- epilogue ----
    const float rinv = 1.0f / l_run;
#pragma unroll
    for (int r = 0; r < 4; ++r) {
        const float inv = __shfl(rinv, (l >> 4) * 4 + r);
        const int mrow = b * SEQ + q0g + w * 16 + (l >> 4) * 4 + r;
        const size_t base = (size_t)mrow * 768 + h * 64 + prow;
#pragma unroll
        for (int i = 0; i < 4; ++i) {
            const float o = pv[i][r] * inv;
            const uint hu = bfr(o);
            const float hf = __uint_as_float(hu << 16);
            const uint lu = bfr(o - hf);
            aoh[base + 16 * i] = (ushort)hu;
            aol[base + 16 * i] = (ushort)lu;
        }
    }
}

// ---------------------------------------------------------------------------
extern "C" void kernel_launch(void* const* d_in, const int* in_sizes, int n_in,
                              void* d_out, int out_size, void* d_ws, size_t ws_size,
                              hipStream_t stream)
{
    const float* hs      = (const float*)d_in[0];
    const int*   pos_row = (const int*)d_in[1];
    const int*   pos_col = (const int*)d_in[2];
    const float* q_w     = (const float*)d_in[3];
    const float* q_b     = (const float*)d_in[4];
    const float* k_w     = (const float*)d_in[5];
    const float* k_b     = (const float*)d_in[6];
    const float* v_w     = (const float*)d_in[7];
    const float* v_b     = (const float*)d_in[8];
    const float* o_w     = (const float*)d_in[9];
    const float* o_b     = (const float*)d_in[10];
    const float* rel_tab = (const float*)d_in[11];

    char* ws = (char*)d_ws;
    const size_t HS_N = (size_t)MTOT * EMB;
    const size_t W_N  = (size_t)EMB * EMB;
    ushort* hsh = (ushort*)ws;  ws += HS_N * 2;
    ushort* hsl = (ushort*)ws;  ws += HS_N * 2;
    ushort* wch = (ushort*)ws;  ws += 3 * W_N * 2;
    ushort* wcl = (ushort*)ws;  ws += 3 * W_N * 2;
    ushort* woh = (ushort*)ws;  ws += W_N * 2;
    ushort* wol = (ushort*)ws;  ws += W_N * 2;
    ushort* aoh = (ushort*)ws;  ws += HS_N * 2;
    ushort* aol = (ushort*)ws;  ws += HS_N * 2;
    ushort* q16 = (ushort*)ws;  ws += HS_N * 2;
    ushort* k16 = (ushort*)ws;  ws += HS_N * 2;
    ushort* vT16 = (ushort*)ws; ws += HS_N * 2;

    split_f32<<<(int)(HS_N / 4 / 256), 256, 0, stream>>>(hs, hsh, hsl, (int)(HS_N / 4));
    split_w4<<<dim3((int)(W_N / 4 / 256), 4), 256, 0, stream>>>(
        q_w, k_w, v_w, o_w, wch, wcl, woh, wol, (int)(W_N / 4));

    gemm_mfma<1, 128><<<dim3(MTOT / 128, 2304 / 128), 256, 0, stream>>>(
        hsh, hsl, wch, wcl, q_b, k_b, v_b, q16, k16, vT16, nullptr);

    attn_mfma<<<dim3(SEQ / 64, BATCH * NHEADS), 256, 0, stream>>>(
        q16, k16, vT16, pos_row, pos_col, rel_tab, aoh, aol);

    gemm_mfma<0, 64><<<dim3(MTOT / 64, EMB / 128), 256, 0, stream>>>(
        aoh, aol, woh, wol, o_b, nullptr, nullptr,
        nullptr, nullptr, nullptr, (float*)d_out);
}

// Round 5
// 209.095 us; speedup vs baseline: 3.1584x; 1.0984x over previous
//
#include <hip/hip_runtime.h>

#define NHEADS 12
#define HDIM   64
#define EMB    768
#define SEQ    1024
#define BATCH  4
#define MTOT   (BATCH * SEQ)

typedef __bf16 bf16x8 __attribute__((ext_vector_type(8)));
typedef float  f32x4  __attribute__((ext_vector_type(4)));

#define GLB(p) ((const __attribute__((address_space(1))) uint32_t*)(p))
#define LDS(p) ((__attribute__((address_space(3))) uint32_t*)(p))

__device__ __forceinline__ uint bfr(float f) {  // f32 -> bf16 bits, RNE
    uint u = __float_as_uint(f);
    return (u + 0x7fffu + ((u >> 16) & 1u)) >> 16;
}

// ---------------------------------------------------------------------------
// One launch: split hs (3072 blocks) + 4 weights (576 blocks each) to hi/lo.
// ---------------------------------------------------------------------------
__global__ __launch_bounds__(256) void split_all(
    const float* __restrict__ hs,
    const float* __restrict__ w0, const float* __restrict__ w1,
    const float* __restrict__ w2, const float* __restrict__ w3,
    ushort* __restrict__ hsh, ushort* __restrict__ hsl,
    ushort* __restrict__ wch, ushort* __restrict__ wcl,
    ushort* __restrict__ woh, ushort* __restrict__ wol)
{
    const int bx = blockIdx.x;
    const float* src;
    ushort *hi, *lo;
    int i;
    if (bx < 3072) {                       // hidden states: 786432 float4
        src = hs; hi = hsh; lo = hsl;
        i = bx * 256 + threadIdx.x;
    } else {                               // weights: 147456 float4 each
        const int y = (bx - 3072) / 576;
        const int r = (bx - 3072) - y * 576;
        src = (y == 0) ? w0 : (y == 1) ? w1 : (y == 2) ? w2 : w3;
        hi = (y < 3) ? (wch + (size_t)y * (EMB * EMB)) : woh;
        lo = (y < 3) ? (wcl + (size_t)y * (EMB * EMB)) : wol;
        i = r * 256 + threadIdx.x;
    }
    float4 v = ((const float4*)src)[i];
    float f[4] = {v.x, v.y, v.z, v.w};
    ushort hh[4], ll[4];
#pragma unroll
    for (int j = 0; j < 4; ++j) {
        uint h = bfr(f[j]);
        float hf = __uint_as_float(h << 16);
        ll[j] = (ushort)bfr(f[j] - hf);
        hh[j] = (ushort)h;
    }
    ushort4 hv = {hh[0], hh[1], hh[2], hh[3]};
    ushort4 lv = {ll[0], ll[1], ll[2], ll[3]};
    ((ushort4*)hi)[i] = hv;
    ((ushort4*)lo)[i] = lv;
}

// ---------------------------------------------------------------------------
// MFMA GEMM, double-buffered, 512 threads = 8 waves (2m x 4n), each wave a
// BM/2 x 32 output slice -> 32-VGPR acc keeps us in the 4-waves/SIMD band.
// C = A(Mx768) * W(Nx768)^T, bf16 hi/lo, 3 MFMAs per product, BK=32.
// MODE 1 (BM=128): QKV fused; q,k -> [B,H,S,D] bf16; v -> [B,H,D,S] bf16.
// MODE 0 (BM=64):  f32 [M,768] (o-projection).
// ---------------------------------------------------------------------------
template <int MODE, int BM>
__global__ __launch_bounds__(512) void gemm_mfma(
    const ushort* __restrict__ Ah, const ushort* __restrict__ Al,
    const ushort* __restrict__ Wh, const ushort* __restrict__ Wl,
    const float* __restrict__ b0, const float* __restrict__ b1,
    const float* __restrict__ b2,
    ushort* __restrict__ q16, ushort* __restrict__ k16,
    ushort* __restrict__ vT16, float* __restrict__ o0)
{
    constexpr int SA = BM * 64;          // bytes per A sub-tile (hi or lo)
    constexpr int SB = 8192;             // bytes per W sub-tile
    constexpr int TS = 2 * SA + 2 * SB;  // one buffer
    constexpr int MFRAG = BM / 32;
    constexpr int WMS = BM / 2;

    __shared__ __align__(16) char ldsc[2 * TS];

    const int t  = threadIdx.x;
    const int w  = t >> 6;
    const int l  = t & 63;
    const int m0 = blockIdx.x * BM;
    const int n0 = blockIdx.y * 128;
    const int wm = w >> 2;   // 0..1
    const int wn = w & 3;    // 0..3

    const char* gb[4] = {
        (const char*)Ah + (size_t)m0 * 1536,
        (const char*)Al + (size_t)m0 * 1536,
        (const char*)Wh + (size_t)n0 * 1536,
        (const char*)Wl + (size_t)n0 * 1536};

    // fragment read offsets (within one buffer; slot-XOR swizzled layout)
    int aoff[MFRAG], boff[2];
#pragma unroll
    for (int i = 0; i < MFRAG; ++i) {
        int row = wm * WMS + i * 16 + (l & 15);
        aoff[i] = row * 64 + ((((l >> 4) ^ ((row >> 1) & 3))) << 4);
    }
#pragma unroll
    for (int i = 0; i < 2; ++i) {
        int rn = wn * 32 + i * 16 + (l & 15);
        boff[i] = rn * 64 + ((((l >> 4) ^ ((rn >> 1) & 3))) << 4);
    }

    // stage one K-step into buffer buf (inverse swizzle applied on global src)
    auto stage = [&](int ks, int buf) {
        const size_t kb = (size_t)ks * 64;
        char* dst = ldsc + buf * TS;
#pragma unroll
        for (int tt = 0; tt < 4; ++tt) {
            const int tsz  = (tt < 2) ? SA : SB;
            const int tbas = (tt == 0) ? 0 : (tt == 1) ? SA
                           : (tt == 2) ? 2 * SA : 2 * SA + SB;
#pragma unroll
            for (int p = 0; p < tsz; p += 8192) {
                const int soff = p + t * 16;
                if (soff < tsz) {   // wave-granular predicate (t*16 multiples)
                    const int srow = soff >> 6;
                    const int slot = (soff >> 4) & 3;
                    const size_t go = (size_t)srow * 1536 +
                                      ((slot ^ ((srow >> 1) & 3)) << 4) + kb;
                    __builtin_amdgcn_global_load_lds(GLB(gb[tt] + go),
                                                     LDS(dst + tbas + soff), 16, 0, 0);
                }
            }
        }
    };

    f32x4 acc[MFRAG][2] = {};

    stage(0, 0);
    __syncthreads();

    for (int ks = 0; ks < 24; ++ks) {
        if (ks + 1 < 24) stage(ks + 1, (ks + 1) & 1);

        const char* cur = ldsc + (ks & 1) * TS;
        bf16x8 ah[MFRAG], al[MFRAG], bh[2], bl[2];
#pragma unroll
        for (int i = 0; i < MFRAG; ++i) {
            ah[i] = *(const bf16x8*)(cur + aoff[i]);
            al[i] = *(const bf16x8*)(cur + SA + aoff[i]);
        }
#pragma unroll
        for (int i = 0; i < 2; ++i) {
            bh[i] = *(const bf16x8*)(cur + 2 * SA + boff[i]);
            bl[i] = *(const bf16x8*)(cur + 2 * SA + SB + boff[i]);
        }
#pragma unroll
        for (int i = 0; i < MFRAG; ++i)
#pragma unroll
            for (int j = 0; j < 2; ++j) {
                acc[i][j] = __builtin_amdgcn_mfma_f32_16x16x32_bf16(ah[i], bh[j], acc[i][j], 0, 0, 0);
                acc[i][j] = __builtin_amdgcn_mfma_f32_16x16x32_bf16(ah[i], bl[j], acc[i][j], 0, 0, 0);
                acc[i][j] = __builtin_amdgcn_mfma_f32_16x16x32_bf16(al[i], bh[j], acc[i][j], 0, 0, 0);
            }
        __syncthreads();
    }

    const int mrow_base = m0 + wm * WMS + ((l >> 4) << 2);

    if (MODE == 1) {
        const int which = (n0 >= 1536) ? 2 : (n0 >= 768 ? 1 : 0);
        const float* bp = (which == 0) ? b0 : (which == 1 ? b1 : b2);
        const float scale = (which == 0) ? 0.125f : 1.0f;
        const int nin_base = n0 - which * 768 + wn * 32 + (l & 15);
        if (which == 2) {
            // V^T store: s runs contiguous within acc regs -> ushort4
#pragma unroll
            for (int j = 0; j < 2; ++j) {
                const int n_in = nin_base + j * 16;
                const float bv = b2[n_in];
                const int h = n_in >> 6, d = n_in & 63;
#pragma unroll
                for (int i = 0; i < MFRAG; ++i) {
                    const int m = mrow_base + i * 16;
                    const int bb = m >> 10, s = m & 1023;
                    ushort4 pk = {(ushort)bfr(acc[i][j][0] + bv),
                                  (ushort)bfr(acc[i][j][1] + bv),
                                  (ushort)bfr(acc[i][j][2] + bv),
                                  (ushort)bfr(acc[i][j][3] + bv)};
                    *(ushort4*)(vT16 + (size_t)((bb * NHEADS + h) * HDIM + d) * SEQ + s) = pk;
                }
            }
        } else {
            ushort* op = (which == 0) ? q16 : k16;
#pragma unroll
            for (int j = 0; j < 2; ++j) {
                const int n_in = nin_base + j * 16;
                const float bv = bp[n_in];
                const int h = n_in >> 6, d = n_in & 63;
#pragma unroll
                for (int i = 0; i < MFRAG; ++i)
#pragma unroll
                    for (int r = 0; r < 4; ++r) {
                        const int m = mrow_base + i * 16 + r;
                        const int bb = m >> 10, s = m & 1023;
                        op[(size_t)((bb * NHEADS + h) * SEQ + s) * HDIM + d] =
                            (ushort)bfr((acc[i][j][r] + bv) * scale);
                    }
            }
        }
    } else {
        const int nin_base = n0 + wn * 32 + (l & 15);
#pragma unroll
        for (int j = 0; j < 2; ++j) {
            const int n_in = nin_base + j * 16;
            const float bv = b0[n_in];
#pragma unroll
            for (int i = 0; i < MFRAG; ++i)
#pragma unroll
                for (int r = 0; r < 4; ++r) {
                    const int m = mrow_base + i * 16 + r;
                    o0[(size_t)m * 768 + n_in] = acc[i][j][r] + bv;
                }
        }
    }
}

// ---------------------------------------------------------------------------
// Flash attention, bf16 MFMA, double-buffered K/V (unchanged from round 4).
// ---------------------------------------------------------------------------
#define QPOFF  0
#define KOFF   8192
#define VOFF   24576
#define POSOFF 40960

__global__ __launch_bounds__(256) void attn_mfma(
    const ushort* __restrict__ q16, const ushort* __restrict__ k16,
    const ushort* __restrict__ vT16, const int* __restrict__ pos_row,
    const int* __restrict__ pos_col, const float* __restrict__ rel_table,
    ushort* __restrict__ aoh, ushort* __restrict__ aol)
{
    __shared__ __align__(16) char lds[41472];

    const int t  = threadIdx.x;
    const int w  = t >> 6;
    const int l  = t & 63;
    const int bh = blockIdx.y;
    const int b  = bh / NHEADS;
    const int h  = bh - b * NHEADS;
    const int q0g = blockIdx.x * 64;

    const char* qb  = (const char*)(q16 + (size_t)bh * SEQ * HDIM);
    const char* kb  = (const char*)(k16 + (size_t)bh * SEQ * HDIM);
    const char* vtb = (const char*)(vT16 + (size_t)bh * HDIM * SEQ);

    const float t0 = rel_table[0 * NHEADS + h];
    const float t1 = rel_table[1 * NHEADS + h];
    const float t2 = rel_table[2 * NHEADS + h];
    const float t3 = rel_table[3 * NHEADS + h];

    const int o1 = t * 16, o2 = o1 + 4096;
    const int r1 = o1 >> 7, r2 = o2 >> 7;
    const int kq1 = o1 ^ ((r1 & 7) << 4);
    const int kq2 = o2 ^ ((r2 & 7) << 4);
    const int vs1 = r1 * 2048 + (((((o1 >> 4) & 7) ^ (r1 & 7))) << 4);
    const int vs2 = r2 * 2048 + (((((o2 >> 4) & 7) ^ (r2 & 7))) << 4);

    auto stage_kv = [&](int kt, int buf) {
        const int k0g = kt * 64;
        __builtin_amdgcn_global_load_lds(GLB(kb + (size_t)k0g * 128 + kq1),
                                         LDS(lds + KOFF + buf * 8192 + w * 1024), 16, 0, 0);
        __builtin_amdgcn_global_load_lds(GLB(kb + (size_t)k0g * 128 + kq2),
                                         LDS(lds + KOFF + buf * 8192 + w * 1024 + 4096), 16, 0, 0);
        __builtin_amdgcn_global_load_lds(GLB(vtb + (size_t)k0g * 2 + vs1),
                                         LDS(lds + VOFF + buf * 8192 + w * 1024), 16, 0, 0);
        __builtin_amdgcn_global_load_lds(GLB(vtb + (size_t)k0g * 2 + vs2),
                                         LDS(lds + VOFF + buf * 8192 + w * 1024 + 4096), 16, 0, 0);
        if (t < 64) {
            int pr = pos_row[b * SEQ + k0g + t];
            int pc = pos_col[b * SEQ + k0g + t];
            *(int*)(lds + POSOFF + buf * 256 + t * 4) = (pr << 8) | pc;
        }
    };

    __builtin_amdgcn_global_load_lds(GLB(qb + (size_t)q0g * 128 + kq1),
                                     LDS(lds + QPOFF + w * 1024), 16, 0, 0);
    __builtin_amdgcn_global_load_lds(GLB(qb + (size_t)q0g * 128 + kq2),
                                     LDS(lds + QPOFF + w * 1024 + 4096), 16, 0, 0);
    stage_kv(0, 0);

    const int qrow_g = q0g + w * 16 + (l & 15);
    const int pq = (pos_row[b * SEQ + qrow_g] << 8) | pos_col[b * SEQ + qrow_g];

    __syncthreads();

    bf16x8 qf[2];
    const int qrl = w * 16 + (l & 15);
#pragma unroll
    for (int ks = 0; ks < 2; ++ks)
        qf[ks] = *(const bf16x8*)(lds + QPOFF + qrl * 128 +
                                  ((((l >> 4) + 4 * ks) ^ (qrl & 7)) << 4));

    f32x4 pv[4] = {};
    float m_run = -1e30f, l_run = 0.0f;

    const int prow = l & 15;
    const int pswz = (prow & 7) << 4;
    const int pwbase = QPOFF + w * 2048 + prow * 128;

    for (int kt = 0; kt < 16; ++kt) {
        const int cb = kt & 1;
        if (kt + 1 < 16) stage_kv(kt + 1, cb ^ 1);
        const char* kbuf = lds + KOFF + cb * 8192;
        const char* vbuf = lds + VOFF + cb * 8192;
        const char* pbuf = lds + POSOFF + cb * 256;

        f32x4 sacc[4] = {};
#pragma unroll
        for (int ks = 0; ks < 2; ++ks) {
            const bf16x8 qq = qf[ks];
#pragma unroll
            for (int j = 0; j < 4; ++j) {
                const int krow = j * 16 + (l & 15);
                const bf16x8 kf = *(const bf16x8*)(kbuf + krow * 128 +
                                                   ((((l >> 4) + 4 * ks) ^ (krow & 7)) << 4));
                sacc[j] = __builtin_amdgcn_mfma_f32_16x16x32_bf16(kf, qq, sacc[j], 0, 0, 0);
            }
        }

        int4 pk4[4];
#pragma unroll
        for (int j = 0; j < 4; ++j)
            pk4[j] = *(const int4*)(pbuf + (l >> 4) * 16 + j * 64);

        float sv[16];
#pragma unroll
        for (int j = 0; j < 4; ++j) {
            const int pkk[4] = {pk4[j].x, pk4[j].y, pk4[j].z, pk4[j].w};
#pragma unroll
            for (int r = 0; r < 4; ++r) {
                const int dd = pq ^ pkk[r];
                const float bs = ((dd & 0xFF00) == 0)
                                     ? (((dd & 0xFF) == 0) ? t3 : t1)
                                     : (((dd & 0xFF) == 0) ? t2 : t0);
                sv[j * 4 + r] = sacc[j][r] + bs;
            }
        }
        float pm = sv[0];
#pragma unroll
        for (int i = 1; i < 16; ++i) pm = fmaxf(pm, sv[i]);
        pm = fmaxf(pm, __shfl_xor(pm, 16));
        pm = fmaxf(pm, __shfl_xor(pm, 32));
        const float mnew = fmaxf(m_run, pm);
        float psum = 0.0f;
#pragma unroll
        for (int i = 0; i < 16; ++i) {
            sv[i] = __expf(sv[i] - mnew);
            psum += sv[i];
        }
        psum += __shfl_xor(psum, 16);
        psum += __shfl_xor(psum, 32);
        const float alpha = __expf(m_run - mnew);
        l_run = l_run * alpha + psum;
        m_run = mnew;

#pragma unroll
        for (int r = 0; r < 4; ++r) {
            const float ar = __shfl(alpha, (l >> 4) * 4 + r);
#pragma unroll
            for (int i = 0; i < 4; ++i) pv[i][r] *= ar;
        }

#pragma unroll
        for (int j = 0; j < 4; ++j)
#pragma unroll
            for (int p2 = 0; p2 < 2; ++p2) {
                const uint u = bfr(sv[j * 4 + 2 * p2]) | (bfr(sv[j * 4 + 2 * p2 + 1]) << 16);
                const int adr = pwbase + (((l >> 4) * 8 + 4 * p2 + 32 * j) ^ pswz);
                *(uint*)(lds + adr) = u;
            }

#pragma unroll
        for (int ks = 0; ks < 2; ++ks) {
            const bf16x8 pf = *(const bf16x8*)(lds + pwbase +
                                               ((((l >> 4) + 4 * ks) << 4) ^ pswz));
#pragma unroll
            for (int i = 0; i < 4; ++i) {
                const int vrow = i * 16 + (l & 15);
                const bf16x8 vf = *(const bf16x8*)(vbuf + vrow * 128 +
                                                   ((((l >> 4) + 4 * ks) ^ (vrow & 7)) << 4));
                pv[i] = __builtin_amdgcn_mfma_f32_16x16x32_bf16(pf, vf, pv[i], 0, 0, 0);
            }
        }
        __syncthreads();
    }

    const float rinv = 1.0f / l_run;
#pragma unroll
    for (int r = 0; r < 4; ++r) {
        const float inv = __shfl(rinv, (l >> 4) * 4 + r);
        const int mrow = b * SEQ + q0g + w * 16 + (l >> 4) * 4 + r;
        const size_t base = (size_t)mrow * 768 + h * 64 + prow;
#pragma unroll
        for (int i = 0; i < 4; ++i) {
            const float o = pv[i][r] * inv;
            const uint hu = bfr(o);
            const float hf = __uint_as_float(hu << 16);
            const uint lu = bfr(o - hf);
            aoh[base + 16 * i] = (ushort)hu;
            aol[base + 16 * i] = (ushort)lu;
        }
    }
}

// ---------------------------------------------------------------------------
extern "C" void kernel_launch(void* const* d_in, const int* in_sizes, int n_in,
                              void* d_out, int out_size, void* d_ws, size_t ws_size,
                              hipStream_t stream)
{
    const float* hs      = (const float*)d_in[0];
    const int*   pos_row = (const int*)d_in[1];
    const int*   pos_col = (const int*)d_in[2];
    const float* q_w     = (const float*)d_in[3];
    const float* q_b     = (const float*)d_in[4];
    const float* k_w     = (const float*)d_in[5];
    const float* k_b     = (const float*)d_in[6];
    const float* v_w     = (const float*)d_in[7];
    const float* v_b     = (const float*)d_in[8];
    const float* o_w     = (const float*)d_in[9];
    const float* o_b     = (const float*)d_in[10];
    const float* rel_tab = (const float*)d_in[11];

    char* ws = (char*)d_ws;
    const size_t HS_N = (size_t)MTOT * EMB;
    const size_t W_N  = (size_t)EMB * EMB;
    ushort* hsh = (ushort*)ws;  ws += HS_N * 2;
    ushort* hsl = (ushort*)ws;  ws += HS_N * 2;
    ushort* wch = (ushort*)ws;  ws += 3 * W_N * 2;
    ushort* wcl = (ushort*)ws;  ws += 3 * W_N * 2;
    ushort* woh = (ushort*)ws;  ws += W_N * 2;
    ushort* wol = (ushort*)ws;  ws += W_N * 2;
    ushort* aoh = (ushort*)ws;  ws += HS_N * 2;
    ushort* aol = (ushort*)ws;  ws += HS_N * 2;
    ushort* q16 = (ushort*)ws;  ws += HS_N * 2;
    ushort* k16 = (ushort*)ws;  ws += HS_N * 2;
    ushort* vT16 = (ushort*)ws; ws += HS_N * 2;

    split_all<<<3072 + 4 * 576, 256, 0, stream>>>(
        hs, q_w, k_w, v_w, o_w, hsh, hsl, wch, wcl, woh, wol);

    gemm_mfma<1, 128><<<dim3(MTOT / 128, 2304 / 128), 512, 0, stream>>>(
        hsh, hsl, wch, wcl, q_b, k_b, v_b, q16, k16, vT16, nullptr);

    attn_mfma<<<dim3(SEQ / 64, BATCH * NHEADS), 256, 0, stream>>>(
        q16, k16, vT16, pos_row, pos_col, rel_tab, aoh, aol);

    gemm_mfma<0, 64><<<dim3(MTOT / 64, EMB / 128), 512, 0, stream>>>(
        aoh, aol, woh, wol, o_b, nullptr, nullptr,
        nullptr, nullptr, nullptr, (float*)d_out);
}